// Round 3
// baseline (658.473 us; speedup 1.0000x reference)
//
#include <hip/hip_runtime.h>

typedef unsigned short ushort_t;

#define NN   16
#define CINC 128
#define COUTC 128
#define PP   9
#define HH   64
#define WW   64
#define OCH  18   // 2*P offset channels

__device__ __forceinline__ float b2f(ushort_t u) {
    union { unsigned int i; float f; } v; v.i = ((unsigned int)u) << 16; return v.f;
}
__device__ __forceinline__ ushort_t f2b(float f) {
    union { float f; unsigned int i; } v; v.f = f;
    unsigned int u = v.i;
    unsigned int lsb = (u >> 16) & 1u;
    u += 0x7fffu + lsb;
    return (ushort_t)(u >> 16);
}

// ---------------- prep: transpose deform_w, fold BN constants ----------------
__global__ __launch_bounds__(256) void prep_kernel(
    const float* __restrict__ deform_w, // (128,128,3,3) fp32
    const float* __restrict__ gamma,
    const float* __restrict__ beta,
    const float* __restrict__ rmean,
    const float* __restrict__ rvar,
    float* __restrict__ wf,     // [(c*9+p)*128 + o]
    float* __restrict__ scale,  // [128]
    float* __restrict__ shift)  // [128]
{
    int i = blockIdx.x * blockDim.x + threadIdx.x;
    if (i < 147456) {
        int cp = i >> 7, o = i & 127;
        wf[i] = deform_w[o * 1152 + cp];
    }
    if (i < 128) {
        float sc = gamma[i] * rsqrtf(rvar[i] + 1e-5f);
        scale[i] = sc;
        shift[i] = beta[i] - rmean[i] * sc;
    }
}

// ---------------- offset conv: produce sampling positions py/px (fp32) ----------------
// off_pos[n][oc][ho][wo]; oc=2p -> py = dy+ky(p)+ho-1 ; oc=2p+1 -> px = dx+kx(p)+wo-1
__global__ __launch_bounds__(256) void offconv_kernel(
    const float* __restrict__ x,        // (16,128,64,64) fp32
    const float* __restrict__ offset_w, // (18,128,3,3) fp32
    const float* __restrict__ offset_b, // (18,) fp32
    float* __restrict__ off_pos)        // (16,18,64,64) fp32
{
    __shared__ __align__(16) ushort_t sx[CINC * 3 * WW]; // 48 KiB: [c][r][w], bf16
    int b = blockIdx.x;
    int n = b >> 6, ho = b & 63;
    int t = threadIdx.x;

    // stage rows ho-1..ho+1 of all 128 channels (zeros outside), fp32 -> bf16
    for (int i = t; i < (CINC * 3 * WW) / 4; i += 256) {
        int c = i / 48, rem = i - c * 48;
        int r = rem >> 4, w4 = (rem & 15) << 2;
        int row = ho - 1 + r;
        ushort4 v = make_ushort4(0, 0, 0, 0);
        if (row >= 0 && row < HH) {
            float4 f = *(const float4*)(x + (((n * CINC + c) * HH + row) * WW + w4));
            v = make_ushort4(f2b(f.x), f2b(f.y), f2b(f.z), f2b(f.w));
        }
        *(ushort4*)(sx + c * 192 + r * 64 + w4) = v;
    }
    __syncthreads();

    int wo = t & 63;
    int og = __builtin_amdgcn_readfirstlane(t >> 6);
    int start = (og < 2) ? og * 5 : 10 + (og - 2) * 4;   // {0,5,10,14}
    int count = (og < 2) ? 5 : 4;

    float acc[5];
    #pragma unroll
    for (int j = 0; j < 5; ++j) acc[j] = (j < count) ? offset_b[start + j] : 0.f;

    for (int c = 0; c < CINC; ++c) {
        float xv[9];
        #pragma unroll
        for (int r = 0; r < 3; ++r)
            #pragma unroll
            for (int kx = 0; kx < 3; ++kx) {
                int col = wo + kx - 1;
                xv[r * 3 + kx] = (col >= 0 && col < WW) ? b2f(sx[c * 192 + r * 64 + col]) : 0.f;
            }
        #pragma unroll
        for (int j = 0; j < 5; ++j) {
            if (j < count) {
                const float* wr = offset_w + ((start + j) * CINC + c) * 9;
                #pragma unroll
                for (int tap = 0; tap < 9; ++tap) acc[j] += xv[tap] * wr[tap];
            }
        }
    }
    for (int j = 0; j < count; ++j) {
        int oc = start + j;
        int p = oc >> 1, d = oc & 1;
        float add = d ? (float)(p % 3 - 1 + wo) : (float)(p / 3 - 1 + ho);
        off_pos[((n * OCH + oc) * HH + ho) * WW + wo] = acc[j] + add;
    }
}

// ---------------- fused bilinear sample + contraction + BN + SiLU ----------------
__global__ __launch_bounds__(256) void deform_kernel(
    const float* __restrict__ x,          // (16,128,64,64) fp32
    const float* __restrict__ off_pos,    // (16,18,64,64) fp32
    const float* __restrict__ wf,         // [(c*9+p)*128 + o]
    const float* __restrict__ scale,
    const float* __restrict__ shift,
    float* __restrict__ out)              // (16,128,64,64) fp32
{
    __shared__ float sbuf[16][64];        // sampled values, 16 channels x 64 pixels
    int b = blockIdx.x;
    int n = b >> 6, ho = b & 63;
    int t = threadIdx.x;
    int wo = t & 63;
    int ogv = t >> 6;
    int og = __builtin_amdgcn_readfirstlane(ogv);

    float acc[32];
    #pragma unroll
    for (int o = 0; o < 32; ++o) acc[o] = 0.f;

    const float* offp = off_pos + ((long)(n * OCH) * HH + ho) * WW + wo;
    const float* xn = x + (long)n * CINC * HH * WW;

    for (int p = 0; p < PP; ++p) {
        float py = offp[(2 * p) * (HH * WW)];
        float px = offp[(2 * p + 1) * (HH * WW)];
        float y0f = floorf(py), x0f = floorf(px);
        float wy = py - y0f, wx = px - x0f;
        int iy0 = (int)y0f, ix0 = (int)x0f;
        float fy0 = (iy0 >= 0 && iy0 < HH) ? 1.f : 0.f;
        float fy1 = (iy0 >= -1 && iy0 < HH - 1) ? 1.f : 0.f;
        float fx0 = (ix0 >= 0 && ix0 < WW) ? 1.f : 0.f;
        float fx1 = (ix0 >= -1 && ix0 < WW - 1) ? 1.f : 0.f;
        int cy0 = min(max(iy0, 0), HH - 1), cy1 = min(max(iy0 + 1, 0), HH - 1);
        int cx0 = min(max(ix0, 0), WW - 1), cx1 = min(max(ix0 + 1, 0), WW - 1);
        float w00 = (1.f - wy) * (1.f - wx) * fy0 * fx0;
        float w01 = (1.f - wy) * wx * fy0 * fx1;
        float w10 = wy * (1.f - wx) * fy1 * fx0;
        float w11 = wy * wx * fy1 * fx1;
        int o00 = cy0 * WW + cx0, o01 = cy0 * WW + cx1;
        int o10 = cy1 * WW + cx0, o11 = cy1 * WW + cx1;

        for (int cb = 0; cb < 8; ++cb) {
            int cmy = cb * 16 + ogv * 4;            // this thread samples 4 channels
            float s[4];
            #pragma unroll
            for (int j = 0; j < 4; ++j) {
                const float* xc = xn + (cmy + j) * (HH * WW);
                float f00 = xc[o00];
                float f01 = xc[o01];
                float f10 = xc[o10];
                float f11 = xc[o11];
                s[j] = w00 * f00 + w01 * f01 + w10 * f10 + w11 * f11;
            }
            __syncthreads();                        // previous MAC phase done
            #pragma unroll
            for (int j = 0; j < 4; ++j) sbuf[ogv * 4 + j][wo] = s[j];
            __syncthreads();                        // sampled tile visible
            for (int j = 0; j < 16; ++j) {
                float sj = sbuf[j][wo];
                const float* wr = wf + ((cb * 16 + j) * PP + p) * COUTC + og * 32;
                #pragma unroll
                for (int o = 0; o < 32; ++o) acc[o] += sj * wr[o];
            }
        }
    }

    #pragma unroll
    for (int o = 0; o < 32; ++o) {
        int oc = og * 32 + o;
        float v = acc[o] * scale[oc] + shift[oc];
        float r = v / (1.f + __expf(-v));
        out[(((long)n * COUTC + oc) * HH + ho) * WW + wo] = r;
    }
}

extern "C" void kernel_launch(void* const* d_in, const int* in_sizes, int n_in,
                              void* d_out, int out_size, void* d_ws, size_t ws_size,
                              hipStream_t stream) {
    const float* x        = (const float*)d_in[0];
    const float* offset_w = (const float*)d_in[1];
    const float* offset_b = (const float*)d_in[2];
    const float* deform_w = (const float*)d_in[3];
    const float* gamma    = (const float*)d_in[4];
    const float* beta     = (const float*)d_in[5];
    const float* rmean    = (const float*)d_in[6];
    const float* rvar     = (const float*)d_in[7];

    char* ws = (char*)d_ws;
    float* off_pos = (float*)(ws);                 // 16*18*64*64*4 = 4,718,592 B
    float* wf      = (float*)(ws + 4718592);       // 1152*128*4    =   589,824 B
    float* scale   = (float*)(ws + 5308416);       // 512 B
    float* shift   = (float*)(ws + 5308928);       // 512 B
    float* out     = (float*)d_out;

    hipLaunchKernelGGL(prep_kernel, dim3(576), dim3(256), 0, stream,
                       deform_w, gamma, beta, rmean, rvar, wf, scale, shift);
    hipLaunchKernelGGL(offconv_kernel, dim3(1024), dim3(256), 0, stream,
                       x, offset_w, offset_b, off_pos);
    hipLaunchKernelGGL(deform_kernel, dim3(1024), dim3(256), 0, stream,
                       x, off_pos, wf, scale, shift, out);
}

// Round 4
// 384.952 us; speedup vs baseline: 1.7105x; 1.7105x over previous
//
#include <hip/hip_runtime.h>

typedef unsigned short ushort_t;
typedef unsigned int uint_t;
typedef __bf16 bf16x8 __attribute__((ext_vector_type(8)));
typedef float f32x16 __attribute__((ext_vector_type(16)));
typedef short short8v __attribute__((ext_vector_type(8)));
typedef short short4v __attribute__((ext_vector_type(4)));

__device__ __forceinline__ ushort_t f2b(float f) {
    union { float f; uint_t i; } v; v.f = f;
    uint_t u = v.i;
    u += 0x7fffu + ((u >> 16) & 1u);
    return (ushort_t)(u >> 16);
}
// pack two fp32 -> one dword of two bf16 (RNE), a in low half
__device__ __forceinline__ uint_t pack_bf2(float a, float b) {
    union { float f; uint_t u; } A, B; A.f = a; B.f = b;
    uint_t ua = A.u + (0x7fffu + ((A.u >> 16) & 1u));
    uint_t ub = B.u + (0x7fffu + ((B.u >> 16) & 1u));
    return (ua >> 16) | (ub & 0xffff0000u);
}
union V8 { short8v v; uint_t d[4]; };
__device__ __forceinline__ void unpack8(short8v vv, float* f) {
    V8 u; u.v = vv;
    #pragma unroll
    for (int i = 0; i < 4; ++i) {
        union { uint_t u; float f; } lo, hi;
        lo.u = u.d[i] << 16;
        hi.u = u.d[i] & 0xffff0000u;
        f[2 * i] = lo.f; f[2 * i + 1] = hi.f;
    }
}

// ---------------- xt: NCHW fp32 -> NHWC bf16 ----------------
__global__ __launch_bounds__(256) void xt_kernel(
    const float* __restrict__ x, ushort_t* __restrict__ xt)
{
    __shared__ __align__(16) ushort_t tile[64 * 132];
    int b = blockIdx.x;
    int n = b >> 6, h = b & 63;
    int t = threadIdx.x;
    int w = t & 63, c4 = t >> 6;
    for (int cb = 0; cb < 32; ++cb) {
        int c = cb * 4 + c4;
        tile[w * 132 + c] = f2b(x[((n * 128 + c) * 64 + h) * 64 + w]);
    }
    __syncthreads();
    for (int it = 0; it < 4; ++it) {
        int idx = it * 2048 + t * 8;     // 8 ushorts per chunk
        int ww = idx >> 7, cc = idx & 127;
        short4v lo = *(const short4v*)(&tile[ww * 132 + cc]);
        short4v hi = *(const short4v*)(&tile[ww * 132 + cc + 4]);
        ushort_t* dst = xt + ((n * 64 + h) * 64 + ww) * 128 + cc;
        *(short4v*)(dst) = lo;
        *(short4v*)(dst + 4) = hi;
    }
}

// ---------------- prep: pack weights, fold BN ----------------
__global__ __launch_bounds__(256) void prep_kernel(
    const float* __restrict__ deform_w,   // (128,128,3,3)
    const float* __restrict__ offset_w,   // (18,128,3,3)
    const float* __restrict__ gamma,
    const float* __restrict__ beta,
    const float* __restrict__ rmean,
    const float* __restrict__ rvar,
    ushort_t* __restrict__ wA,   // [p][cout][c] bf16
    float* __restrict__ wO,      // [tap][c][oc=18] fp32
    float* __restrict__ scale,
    float* __restrict__ shift)
{
    int i = blockIdx.x * blockDim.x + threadIdx.x;
    if (i < 147456) {
        int p = i >> 14, o = (i >> 7) & 127, c = i & 127;
        wA[i] = f2b(deform_w[o * 1152 + c * 9 + p]);
    }
    if (i < 20736) {
        int oc = i % 18; int rest = i / 18;
        int c = rest & 127, tap = rest >> 7;
        wO[i] = offset_w[oc * 1152 + c * 9 + tap];
    }
    if (i < 128) {
        float sc = gamma[i] * rsqrtf(rvar[i] + 1e-5f);
        scale[i] = sc;
        shift[i] = beta[i] - rmean[i] * sc;
    }
}

// ---------------- offset conv from xt (channels-last) ----------------
__global__ __launch_bounds__(256) void offconv_kernel(
    const ushort_t* __restrict__ xt,    // (16,64,64,128) bf16
    const float* __restrict__ wO,       // [tap][c][18]
    const float* __restrict__ offset_b, // (18,)
    float* __restrict__ off_pos)        // (16,18,64,64) fp32
{
    __shared__ __align__(16) ushort_t sx[3 * 64 * 128];   // [rw=r*64+col][c, XOR-swizzled 8-granules]
    int b = blockIdx.x;
    int n = b >> 6, ho = b & 63;
    int t = threadIdx.x;

    for (int i = t; i < 3072; i += 256) {     // 3072 chunks of 8 ushorts
        int rw = i >> 4, g = i & 15;
        int row = ho - 1 + (rw >> 6);
        int gp = g ^ (rw & 15);
        short8v v = {0, 0, 0, 0, 0, 0, 0, 0};
        if (row >= 0 && row < 64)
            v = *(const short8v*)(xt + ((n * 64 + row) * 64 + (rw & 63)) * 128 + g * 8);
        *(short8v*)(&sx[rw * 128 + gp * 8]) = v;
    }
    __syncthreads();

    int pix = t & 63;
    int q = __builtin_amdgcn_readfirstlane(t >> 6);   // c-quarter, wave-uniform

    float acc[18];
    #pragma unroll
    for (int oc = 0; oc < 18; ++oc) acc[oc] = 0.f;

    for (int tap = 0; tap < 9; ++tap) {
        int r = tap / 3, kx = tap % 3;
        int col = pix + kx - 1;
        if (col >= 0 && col < 64) {
            int rw = r * 64 + col;
            #pragma unroll
            for (int cg = 0; cg < 4; ++cg) {
                int g = q * 4 + cg;
                int gp = g ^ (rw & 15);
                short8v v = *(const short8v*)(&sx[rw * 128 + gp * 8]);
                float xf[8];
                unpack8(v, xf);
                const float* wp = wO + (tap * 128 + q * 32 + cg * 8) * 18;
                #pragma unroll
                for (int j = 0; j < 8; ++j)
                    #pragma unroll
                    for (int oc = 0; oc < 18; ++oc)
                        acc[oc] += xf[j] * wp[j * 18 + oc];
            }
        }
    }
    __syncthreads();
    float* part = (float*)sx;    // [4][18][64] fp32 partials
    #pragma unroll
    for (int oc = 0; oc < 18; ++oc) part[(q * 18 + oc) * 64 + pix] = acc[oc];
    __syncthreads();
    for (int i = t; i < 1152; i += 256) {
        int oc = i >> 6, px = i & 63;
        float s = part[oc * 64 + px] + part[(18 + oc) * 64 + px]
                + part[(36 + oc) * 64 + px] + part[(54 + oc) * 64 + px]
                + offset_b[oc];
        int p = oc >> 1, d = oc & 1;
        float add = d ? (float)(p % 3 - 1 + px) : (float)(p / 3 - 1 + ho);
        off_pos[((n * 18 + oc) * 64 + ho) * 64 + px] = s + add;
    }
}

// ---------------- fused bilinear sample + MFMA GEMM + BN + SiLU ----------------
// block = (n, ho-pair): 128 pixels x 128 couts, K = 9p x 128c
__global__ __launch_bounds__(256, 2) void deform_kernel(
    const ushort_t* __restrict__ xt,      // (16,64,64,128) bf16
    const float* __restrict__ off_pos,    // (16,18,64,64) fp32
    const ushort_t* __restrict__ wA,      // [p][cout][c] bf16
    const float* __restrict__ scale,
    const float* __restrict__ shift,
    float* __restrict__ out)              // (16,128,64,64) fp32
{
    __shared__ __align__(16) ushort_t S[128 * 128];   // [pix][c], XOR-swizzled 8-granules
    int b = blockIdx.x;
    int n = b >> 5, ho0 = (b & 31) << 1;
    int t = threadIdx.x;
    int lane = t & 63;
    int wv = __builtin_amdgcn_readfirstlane(t >> 6);
    int mh = wv >> 1, nh = wv & 1;        // wave tile: cout mh*64.. , pix nh*64..
    int pix_s = t & 127, ch = t >> 7;     // sampling role: pixel + c-half
    int row_s = pix_s >> 6, wo_s = pix_s & 63;
    int ho_s = ho0 + row_s;

    f32x16 acc[2][2];
    #pragma unroll
    for (int mt = 0; mt < 2; ++mt)
        #pragma unroll
        for (int nt = 0; nt < 2; ++nt)
            #pragma unroll
            for (int r = 0; r < 16; ++r) acc[mt][nt][r] = 0.f;

    const ushort_t* xn = xt + n * (64 * 64 * 128);

    for (int p = 0; p < 9; ++p) {
        // --- A prefetch (registers), overlapped with sampling ---
        bf16x8 afrag[2][8];
        const ushort_t* wAp = wA + p * (128 * 128);
        #pragma unroll
        for (int mt = 0; mt < 2; ++mt) {
            int cout = mh * 64 + mt * 32 + (lane & 31);
            #pragma unroll
            for (int ks = 0; ks < 8; ++ks)
                afrag[mt][ks] = *(const bf16x8*)(wAp + cout * 128 + ks * 16 + ((lane >> 5) << 3));
        }
        // --- sampling: this thread handles 64 channels of one pixel ---
        float py = off_pos[((n * 18 + 2 * p) * 64 + ho_s) * 64 + wo_s];
        float px = off_pos[((n * 18 + 2 * p + 1) * 64 + ho_s) * 64 + wo_s];
        float y0f = floorf(py), x0f = floorf(px);
        float wy = py - y0f, wx = px - x0f;
        int iy0 = (int)y0f, ix0 = (int)x0f;
        float fy0 = (iy0 >= 0 && iy0 < 64) ? 1.f : 0.f;
        float fy1 = (iy0 >= -1 && iy0 < 63) ? 1.f : 0.f;
        float fx0 = (ix0 >= 0 && ix0 < 64) ? 1.f : 0.f;
        float fx1 = (ix0 >= -1 && ix0 < 63) ? 1.f : 0.f;
        int cy0 = min(max(iy0, 0), 63), cy1 = min(max(iy0 + 1, 0), 63);
        int cx0 = min(max(ix0, 0), 63), cx1 = min(max(ix0 + 1, 0), 63);
        float w00 = (1.f - wy) * (1.f - wx) * fy0 * fx0;
        float w01 = (1.f - wy) * wx * fy0 * fx1;
        float w10 = wy * (1.f - wx) * fy1 * fx0;
        float w11 = wy * wx * fy1 * fx1;
        const ushort_t* p00 = xn + (cy0 * 64 + cx0) * 128 + ch * 64;
        const ushort_t* p01 = xn + (cy0 * 64 + cx1) * 128 + ch * 64;
        const ushort_t* p10 = xn + (cy1 * 64 + cx0) * 128 + ch * 64;
        const ushort_t* p11 = xn + (cy1 * 64 + cx1) * 128 + ch * 64;
        #pragma unroll
        for (int g = 0; g < 8; ++g) {
            int cc = g * 8;
            short8v v00 = *(const short8v*)(p00 + cc);
            short8v v01 = *(const short8v*)(p01 + cc);
            short8v v10 = *(const short8v*)(p10 + cc);
            short8v v11 = *(const short8v*)(p11 + cc);
            float f00[8], f01[8], f10[8], f11[8];
            unpack8(v00, f00); unpack8(v01, f01);
            unpack8(v10, f10); unpack8(v11, f11);
            float s[8];
            #pragma unroll
            for (int j = 0; j < 8; ++j)
                s[j] = w00 * f00[j] + w01 * f01[j] + w10 * f10[j] + w11 * f11[j];
            uint4 pk;
            pk.x = pack_bf2(s[0], s[1]); pk.y = pack_bf2(s[2], s[3]);
            pk.z = pack_bf2(s[4], s[5]); pk.w = pack_bf2(s[6], s[7]);
            int gg = (ch * 8 + g) ^ (pix_s & 15);
            *(uint4*)(&S[pix_s * 128 + gg * 8]) = pk;
        }
        __syncthreads();
        // --- GEMM: 8 k-steps over this p's 128 channels ---
        #pragma unroll
        for (int ks = 0; ks < 8; ++ks) {
            bf16x8 bfrag[2];
            #pragma unroll
            for (int nt = 0; nt < 2; ++nt) {
                int pixb = nh * 64 + nt * 32 + (lane & 31);
                int g = ks * 2 + (lane >> 5);
                int gg = g ^ (pixb & 15);
                bfrag[nt] = *(const bf16x8*)(&S[pixb * 128 + gg * 8]);
            }
            #pragma unroll
            for (int mt = 0; mt < 2; ++mt)
                #pragma unroll
                for (int nt = 0; nt < 2; ++nt)
                    acc[mt][nt] = __builtin_amdgcn_mfma_f32_32x32x16_bf16(
                        afrag[mt][ks], bfrag[nt], acc[mt][nt], 0, 0, 0);
        }
        __syncthreads();   // before next p overwrites S
    }

    // --- epilogue: BN + SiLU, fp32 out ---
    #pragma unroll
    for (int mt = 0; mt < 2; ++mt) {
        #pragma unroll
        for (int nt = 0; nt < 2; ++nt) {
            int pixb = nh * 64 + nt * 32 + (lane & 31);
            int hoo = ho0 + (pixb >> 6), woo = pixb & 63;
            #pragma unroll
            for (int r = 0; r < 16; ++r) {
                int cout = mh * 64 + mt * 32 + (r & 3) + 8 * (r >> 2) + 4 * (lane >> 5);
                float v = acc[mt][nt][r] * scale[cout] + shift[cout];
                float rr = v / (1.f + __expf(-v));
                out[((n * 128 + cout) * 64 + hoo) * 64 + woo] = rr;
            }
        }
    }
}

extern "C" void kernel_launch(void* const* d_in, const int* in_sizes, int n_in,
                              void* d_out, int out_size, void* d_ws, size_t ws_size,
                              hipStream_t stream) {
    const float* x        = (const float*)d_in[0];
    const float* offset_w = (const float*)d_in[1];
    const float* offset_b = (const float*)d_in[2];
    const float* deform_w = (const float*)d_in[3];
    const float* gamma    = (const float*)d_in[4];
    const float* beta     = (const float*)d_in[5];
    const float* rmean    = (const float*)d_in[6];
    const float* rvar     = (const float*)d_in[7];

    char* ws = (char*)d_ws;
    float*    off_pos = (float*)(ws);                    //  4,718,592 B
    ushort_t* xt      = (ushort_t*)(ws + 4718592);       // 16,777,216 B
    ushort_t* wA      = (ushort_t*)(ws + 21495808);      //    294,912 B
    float*    wO      = (float*)(ws + 21790720);         //     82,944 B
    float*    scale   = (float*)(ws + 21873664);         //        512 B
    float*    shift   = (float*)(ws + 21874176);         //        512 B
    float*    out     = (float*)d_out;

    hipLaunchKernelGGL(prep_kernel, dim3(576), dim3(256), 0, stream,
                       deform_w, offset_w, gamma, beta, rmean, rvar, wA, wO, scale, shift);
    hipLaunchKernelGGL(xt_kernel, dim3(1024), dim3(256), 0, stream, x, xt);
    hipLaunchKernelGGL(offconv_kernel, dim3(1024), dim3(256), 0, stream,
                       xt, wO, offset_b, off_pos);
    hipLaunchKernelGGL(deform_kernel, dim3(512), dim3(256), 0, stream,
                       xt, off_pos, wA, scale, shift, out);
}

// Round 5
// 295.543 us; speedup vs baseline: 2.2280x; 1.3025x over previous
//
#include <hip/hip_runtime.h>

typedef unsigned short ushort_t;
typedef unsigned int uint_t;
typedef __bf16 bf16x8 __attribute__((ext_vector_type(8)));
typedef float f32x16 __attribute__((ext_vector_type(16)));
typedef short short8v __attribute__((ext_vector_type(8)));
typedef short short4v __attribute__((ext_vector_type(4)));

__device__ __forceinline__ ushort_t f2b(float f) {
    union { float f; uint_t i; } v; v.f = f;
    uint_t u = v.i;
    u += 0x7fffu + ((u >> 16) & 1u);
    return (ushort_t)(u >> 16);
}
__device__ __forceinline__ uint_t pack_bf2(float a, float b) {
    union { float f; uint_t u; } A, B; A.f = a; B.f = b;
    uint_t ua = A.u + (0x7fffu + ((A.u >> 16) & 1u));
    uint_t ub = B.u + (0x7fffu + ((B.u >> 16) & 1u));
    return (ua >> 16) | (ub & 0xffff0000u);
}
union V8 { short8v v; uint_t d[4]; };
__device__ __forceinline__ void unpack8(short8v vv, float* f) {
    V8 u; u.v = vv;
    #pragma unroll
    for (int i = 0; i < 4; ++i) {
        union { uint_t u; float f; } lo, hi;
        lo.u = u.d[i] << 16;
        hi.u = u.d[i] & 0xffff0000u;
        f[2 * i] = lo.f; f[2 * i + 1] = hi.f;
    }
}
__device__ __forceinline__ uint4 blend_pack(short8v a, short8v b, short8v c, short8v d,
                                            float w00, float w01, float w10, float w11) {
    float f00[8], f01[8], f10[8], f11[8], s[8];
    unpack8(a, f00); unpack8(b, f01); unpack8(c, f10); unpack8(d, f11);
    #pragma unroll
    for (int j = 0; j < 8; ++j)
        s[j] = w00 * f00[j] + w01 * f01[j] + w10 * f10[j] + w11 * f11[j];
    uint4 pk;
    pk.x = pack_bf2(s[0], s[1]); pk.y = pack_bf2(s[2], s[3]);
    pk.z = pack_bf2(s[4], s[5]); pk.w = pack_bf2(s[6], s[7]);
    return pk;
}

// ---------------- xt: NCHW fp32 -> NHWC bf16  (+ folded prep) ----------------
__global__ __launch_bounds__(256) void xt_prep_kernel(
    const float* __restrict__ x, ushort_t* __restrict__ xt,
    const float* __restrict__ deform_w,   // (128,128,3,3)
    const float* __restrict__ offset_w,   // (18,128,3,3)
    const float* __restrict__ gamma,
    const float* __restrict__ beta,
    const float* __restrict__ rmean,
    const float* __restrict__ rvar,
    ushort_t* __restrict__ wA,   // [p][cout][c] bf16
    float* __restrict__ wO,      // [tap][c][18] fp32
    float* __restrict__ scale,
    float* __restrict__ shift)
{
    __shared__ __align__(16) ushort_t tile[64 * 132];
    int braw = blockIdx.x;
    int b = (braw & 7) * 128 + (braw >> 3);   // XCD slab swizzle: XCD k -> n {2k,2k+1}
    int n = b >> 6, h = b & 63;
    int t = threadIdx.x;

    // ---- folded prep (raw block index) ----
    int i = braw * 256 + t;
    if (i < 147456) {
        int p = i >> 14, o = (i >> 7) & 127, c = i & 127;
        wA[i] = f2b(deform_w[o * 1152 + c * 9 + p]);
    }
    if (i < 20736) {
        int oc = i % 18; int rest = i / 18;
        int c = rest & 127, tap = rest >> 7;
        wO[i] = offset_w[oc * 1152 + c * 9 + tap];
    }
    if (i < 128) {
        float sc = gamma[i] * rsqrtf(rvar[i] + 1e-5f);
        scale[i] = sc;
        shift[i] = beta[i] - rmean[i] * sc;
    }

    // ---- transpose ----
    int w = t & 63, c4 = t >> 6;
    for (int cb = 0; cb < 32; ++cb) {
        int c = cb * 4 + c4;
        tile[w * 132 + c] = f2b(x[((n * 128 + c) * 64 + h) * 64 + w]);
    }
    __syncthreads();
    for (int it = 0; it < 4; ++it) {
        int idx = it * 2048 + t * 8;
        int ww = idx >> 7, cc = idx & 127;
        short4v lo = *(const short4v*)(&tile[ww * 132 + cc]);
        short4v hi = *(const short4v*)(&tile[ww * 132 + cc + 4]);
        ushort_t* dst = xt + ((n * 64 + h) * 64 + ww) * 128 + cc;
        *(short4v*)(dst) = lo;
        *(short4v*)(dst + 4) = hi;
    }
}

// ---------------- offset conv from xt (channels-last) ----------------
__global__ __launch_bounds__(256) void offconv_kernel(
    const ushort_t* __restrict__ xt,    // (16,64,64,128) bf16
    const float* __restrict__ wO,       // [tap][c][18]
    const float* __restrict__ offset_b, // (18,)
    float* __restrict__ off_pos)        // (16,18,64,64) fp32
{
    __shared__ __align__(16) ushort_t sx[3 * 64 * 128];
    int braw = blockIdx.x;
    int b = (braw & 7) * 128 + (braw >> 3);   // same slab swizzle
    int n = b >> 6, ho = b & 63;
    int t = threadIdx.x;

    for (int i = t; i < 3072; i += 256) {
        int rw = i >> 4, g = i & 15;
        int row = ho - 1 + (rw >> 6);
        int gp = g ^ (rw & 15);
        short8v v = {0, 0, 0, 0, 0, 0, 0, 0};
        if (row >= 0 && row < 64)
            v = *(const short8v*)(xt + ((n * 64 + row) * 64 + (rw & 63)) * 128 + g * 8);
        *(short8v*)(&sx[rw * 128 + gp * 8]) = v;
    }
    __syncthreads();

    int pix = t & 63;
    int q = __builtin_amdgcn_readfirstlane(t >> 6);

    float acc[18];
    #pragma unroll
    for (int oc = 0; oc < 18; ++oc) acc[oc] = 0.f;

    for (int tap = 0; tap < 9; ++tap) {
        int r = tap / 3, kx = tap % 3;
        int col = pix + kx - 1;
        if (col >= 0 && col < 64) {
            int rw = r * 64 + col;
            #pragma unroll
            for (int cg = 0; cg < 4; ++cg) {
                int g = q * 4 + cg;
                int gp = g ^ (rw & 15);
                short8v v = *(const short8v*)(&sx[rw * 128 + gp * 8]);
                float xf[8];
                unpack8(v, xf);
                const float* wp = wO + (tap * 128 + q * 32 + cg * 8) * 18;
                #pragma unroll
                for (int j = 0; j < 8; ++j)
                    #pragma unroll
                    for (int oc = 0; oc < 18; ++oc)
                        acc[oc] += xf[j] * wp[j * 18 + oc];
            }
        }
    }
    __syncthreads();
    float* part = (float*)sx;
    #pragma unroll
    for (int oc = 0; oc < 18; ++oc) part[(q * 18 + oc) * 64 + pix] = acc[oc];
    __syncthreads();
    for (int i = t; i < 1152; i += 256) {
        int oc = i >> 6, px = i & 63;
        float s = part[oc * 64 + px] + part[(18 + oc) * 64 + px]
                + part[(36 + oc) * 64 + px] + part[(54 + oc) * 64 + px]
                + offset_b[oc];
        int p = oc >> 1, d = oc & 1;
        float add = d ? (float)(p % 3 - 1 + px) : (float)(p / 3 - 1 + ho);
        off_pos[((n * 18 + oc) * 64 + ho) * 64 + px] = s + add;
    }
}

// ---------------- fused bilinear sample + MFMA GEMM + BN + SiLU ----------------
// pipelined, double-buffered LDS, one barrier per p
__global__ __launch_bounds__(256, 2) void deform_kernel(
    const ushort_t* __restrict__ xt,      // (16,64,64,128) bf16
    const float* __restrict__ off_pos,    // (16,18,64,64) fp32
    const ushort_t* __restrict__ wA,      // [p][cout][c] bf16
    const float* __restrict__ scale,
    const float* __restrict__ shift,
    float* __restrict__ out)              // (16,128,64,64) fp32
{
    __shared__ __align__(16) ushort_t S[2 * 128 * 128];  // double buffer, 64 KiB
    int braw = blockIdx.x;
    int bs = (braw & 7) * 64 + (braw >> 3);   // XCD k -> n {2k,2k+1}
    int n = bs >> 5, ho0 = (bs & 31) << 1;
    int t = threadIdx.x;
    int lane = t & 63;
    int wv = __builtin_amdgcn_readfirstlane(t >> 6);
    int mh = wv >> 1, nh = wv & 1;
    int pix_s = t & 127, ch = t >> 7;
    int row_s = pix_s >> 6, wo_s = pix_s & 63;
    int ho_s = ho0 + row_s;

    f32x16 acc[2][2];
    #pragma unroll
    for (int mt = 0; mt < 2; ++mt)
        #pragma unroll
        for (int nt = 0; nt < 2; ++nt)
            #pragma unroll
            for (int r = 0; r < 16; ++r) acc[mt][nt][r] = 0.f;

    const ushort_t* xn = xt + n * (64 * 64 * 128);
    const float* opn = off_pos + (long)n * 18 * 4096 + ho_s * 64 + wo_s;

    // current-p state
    float w00, w01, w10, w11;
    const ushort_t *p00, *p01, *p10, *p11;
    short8v v00[4], v01[4], v10[4], v11[4];   // first-half prefetch

    // ---- prologue: p = 0 ----
    {
        float py = opn[0];
        float px = opn[4096];
        float y0f = floorf(py), x0f = floorf(px);
        float wy = py - y0f, wx = px - x0f;
        int iy0 = (int)y0f, ix0 = (int)x0f;
        float fy0 = (iy0 >= 0 && iy0 < 64) ? 1.f : 0.f;
        float fy1 = (iy0 >= -1 && iy0 < 63) ? 1.f : 0.f;
        float fx0 = (ix0 >= 0 && ix0 < 64) ? 1.f : 0.f;
        float fx1 = (ix0 >= -1 && ix0 < 63) ? 1.f : 0.f;
        int cy0 = min(max(iy0, 0), 63), cy1 = min(max(iy0 + 1, 0), 63);
        int cx0 = min(max(ix0, 0), 63), cx1 = min(max(ix0 + 1, 0), 63);
        w00 = (1.f - wy) * (1.f - wx) * fy0 * fx0;
        w01 = (1.f - wy) * wx * fy0 * fx1;
        w10 = wy * (1.f - wx) * fy1 * fx0;
        w11 = wy * wx * fy1 * fx1;
        p00 = xn + (cy0 * 64 + cx0) * 128 + ch * 64;
        p01 = xn + (cy0 * 64 + cx1) * 128 + ch * 64;
        p10 = xn + (cy1 * 64 + cx0) * 128 + ch * 64;
        p11 = xn + (cy1 * 64 + cx1) * 128 + ch * 64;
        #pragma unroll
        for (int g = 0; g < 4; ++g) {
            int cc = g * 8;
            v00[g] = *(const short8v*)(p00 + cc);
            v01[g] = *(const short8v*)(p01 + cc);
            v10[g] = *(const short8v*)(p10 + cc);
            v11[g] = *(const short8v*)(p11 + cc);
        }
    }

    for (int p = 0; p < 9; ++p) {
        ushort_t* buf = &S[(p & 1) * 16384];

        // issue second-half corner loads (in flight during first-half blend)
        short8v u00[4], u01[4], u10[4], u11[4];
        #pragma unroll
        for (int g = 0; g < 4; ++g) {
            int cc = (g + 4) * 8;
            u00[g] = *(const short8v*)(p00 + cc);
            u01[g] = *(const short8v*)(p01 + cc);
            u10[g] = *(const short8v*)(p10 + cc);
            u11[g] = *(const short8v*)(p11 + cc);
        }
        // blend + store first half
        #pragma unroll
        for (int g = 0; g < 4; ++g) {
            uint4 pk = blend_pack(v00[g], v01[g], v10[g], v11[g], w00, w01, w10, w11);
            int gg = (ch * 8 + g) ^ (pix_s & 15);
            *(uint4*)(&buf[pix_s * 128 + gg * 8]) = pk;
        }
        // blend + store second half
        #pragma unroll
        for (int g = 0; g < 4; ++g) {
            uint4 pk = blend_pack(u00[g], u01[g], u10[g], u11[g], w00, w01, w10, w11);
            int gg = (ch * 8 + g + 4) ^ (pix_s & 15);
            *(uint4*)(&buf[pix_s * 128 + gg * 8]) = pk;
        }

        // prefetch next p: positions, weights, first-half corners
        if (p < 8) {
            float py = opn[(2 * p + 2) * 4096];
            float px = opn[(2 * p + 3) * 4096];
            float y0f = floorf(py), x0f = floorf(px);
            float wy = py - y0f, wx = px - x0f;
            int iy0 = (int)y0f, ix0 = (int)x0f;
            float fy0 = (iy0 >= 0 && iy0 < 64) ? 1.f : 0.f;
            float fy1 = (iy0 >= -1 && iy0 < 63) ? 1.f : 0.f;
            float fx0 = (ix0 >= 0 && ix0 < 64) ? 1.f : 0.f;
            float fx1 = (ix0 >= -1 && ix0 < 63) ? 1.f : 0.f;
            int cy0 = min(max(iy0, 0), 63), cy1 = min(max(iy0 + 1, 0), 63);
            int cx0 = min(max(ix0, 0), 63), cx1 = min(max(ix0 + 1, 0), 63);
            w00 = (1.f - wy) * (1.f - wx) * fy0 * fx0;
            w01 = (1.f - wy) * wx * fy0 * fx1;
            w10 = wy * (1.f - wx) * fy1 * fx0;
            w11 = wy * wx * fy1 * fx1;
            p00 = xn + (cy0 * 64 + cx0) * 128 + ch * 64;
            p01 = xn + (cy0 * 64 + cx1) * 128 + ch * 64;
            p10 = xn + (cy1 * 64 + cx0) * 128 + ch * 64;
            p11 = xn + (cy1 * 64 + cx1) * 128 + ch * 64;
            #pragma unroll
            for (int g = 0; g < 4; ++g) {
                int cc = g * 8;
                v00[g] = *(const short8v*)(p00 + cc);
                v01[g] = *(const short8v*)(p01 + cc);
                v10[g] = *(const short8v*)(p10 + cc);
                v11[g] = *(const short8v*)(p11 + cc);
            }
        }

        // A-fragment loads for this p (in flight across barrier)
        bf16x8 afrag[2][8];
        const ushort_t* wAp = wA + p * (128 * 128);
        #pragma unroll
        for (int mt = 0; mt < 2; ++mt) {
            int cout = mh * 64 + mt * 32 + (lane & 31);
            #pragma unroll
            for (int ks = 0; ks < 8; ++ks)
                afrag[mt][ks] = *(const bf16x8*)(wAp + cout * 128 + ks * 16 + ((lane >> 5) << 3));
        }

        __syncthreads();   // stores to buf visible; MFMA p-? readers done (single barrier/iter)

        #pragma unroll
        for (int ks = 0; ks < 8; ++ks) {
            bf16x8 bfrag[2];
            #pragma unroll
            for (int nt = 0; nt < 2; ++nt) {
                int pixb = nh * 64 + nt * 32 + (lane & 31);
                int g = ks * 2 + (lane >> 5);
                int gg = g ^ (pixb & 15);
                bfrag[nt] = *(const bf16x8*)(&buf[pixb * 128 + gg * 8]);
            }
            #pragma unroll
            for (int mt = 0; mt < 2; ++mt)
                #pragma unroll
                for (int nt = 0; nt < 2; ++nt)
                    acc[mt][nt] = __builtin_amdgcn_mfma_f32_32x32x16_bf16(
                        afrag[mt][ks], bfrag[nt], acc[mt][nt], 0, 0, 0);
        }
    }

    // ---- epilogue: BN + SiLU, fp32 out ----
    #pragma unroll
    for (int mt = 0; mt < 2; ++mt) {
        #pragma unroll
        for (int nt = 0; nt < 2; ++nt) {
            int pixb = nh * 64 + nt * 32 + (lane & 31);
            int hoo = ho0 + (pixb >> 6), woo = pixb & 63;
            #pragma unroll
            for (int r = 0; r < 16; ++r) {
                int cout = mh * 64 + mt * 32 + (r & 3) + 8 * (r >> 2) + 4 * (lane >> 5);
                float v = acc[mt][nt][r] * scale[cout] + shift[cout];
                float rr = v / (1.f + __expf(-v));
                out[((n * 128 + cout) * 64 + hoo) * 64 + woo] = rr;
            }
        }
    }
}

extern "C" void kernel_launch(void* const* d_in, const int* in_sizes, int n_in,
                              void* d_out, int out_size, void* d_ws, size_t ws_size,
                              hipStream_t stream) {
    const float* x        = (const float*)d_in[0];
    const float* offset_w = (const float*)d_in[1];
    const float* offset_b = (const float*)d_in[2];
    const float* deform_w = (const float*)d_in[3];
    const float* gamma    = (const float*)d_in[4];
    const float* beta     = (const float*)d_in[5];
    const float* rmean    = (const float*)d_in[6];
    const float* rvar     = (const float*)d_in[7];

    char* ws = (char*)d_ws;
    float*    off_pos = (float*)(ws);                    //  4,718,592 B
    ushort_t* xt      = (ushort_t*)(ws + 4718592);       // 16,777,216 B
    ushort_t* wA      = (ushort_t*)(ws + 21495808);      //    294,912 B
    float*    wO      = (float*)(ws + 21790720);         //     82,944 B
    float*    scale   = (float*)(ws + 21873664);         //        512 B
    float*    shift   = (float*)(ws + 21874176);         //        512 B
    float*    out     = (float*)d_out;

    hipLaunchKernelGGL(xt_prep_kernel, dim3(1024), dim3(256), 0, stream,
                       x, xt, deform_w, offset_w, gamma, beta, rmean, rvar,
                       wA, wO, scale, shift);
    hipLaunchKernelGGL(offconv_kernel, dim3(1024), dim3(256), 0, stream,
                       xt, wO, offset_b, off_pos);
    hipLaunchKernelGGL(deform_kernel, dim3(512), dim3(256), 0, stream,
                       xt, off_pos, wA, scale, shift, out);
}

// Round 6
// 257.992 us; speedup vs baseline: 2.5523x; 1.1456x over previous
//
#include <hip/hip_runtime.h>

typedef unsigned short ushort_t;
typedef unsigned int uint_t;
typedef __bf16 bf16x8 __attribute__((ext_vector_type(8)));
typedef float f32x16 __attribute__((ext_vector_type(16)));
typedef float f32x4 __attribute__((ext_vector_type(4)));
typedef short short8v __attribute__((ext_vector_type(8)));
typedef short short4v __attribute__((ext_vector_type(4)));

__device__ __forceinline__ ushort_t f2b(float f) {
    union { float f; uint_t i; } v; v.f = f;
    uint_t u = v.i;
    u += 0x7fffu + ((u >> 16) & 1u);
    return (ushort_t)(u >> 16);
}
__device__ __forceinline__ uint_t pack_bf2(float a, float b) {
    union { float f; uint_t u; } A, B; A.f = a; B.f = b;
    uint_t ua = A.u + (0x7fffu + ((A.u >> 16) & 1u));
    uint_t ub = B.u + (0x7fffu + ((B.u >> 16) & 1u));
    return (ua >> 16) | (ub & 0xffff0000u);
}
union V8 { short8v v; uint_t d[4]; };
__device__ __forceinline__ void unpack8(short8v vv, float* f) {
    V8 u; u.v = vv;
    #pragma unroll
    for (int i = 0; i < 4; ++i) {
        union { uint_t u; float f; } lo, hi;
        lo.u = u.d[i] << 16;
        hi.u = u.d[i] & 0xffff0000u;
        f[2 * i] = lo.f; f[2 * i + 1] = hi.f;
    }
}
__device__ __forceinline__ uint4 blend_pack(short8v a, short8v b, short8v c, short8v d,
                                            float w00, float w01, float w10, float w11) {
    float f00[8], f01[8], f10[8], f11[8], s[8];
    unpack8(a, f00); unpack8(b, f01); unpack8(c, f10); unpack8(d, f11);
    #pragma unroll
    for (int j = 0; j < 8; ++j)
        s[j] = w00 * f00[j] + w01 * f01[j] + w10 * f10[j] + w11 * f11[j];
    uint4 pk;
    pk.x = pack_bf2(s[0], s[1]); pk.y = pack_bf2(s[2], s[3]);
    pk.z = pack_bf2(s[4], s[5]); pk.w = pack_bf2(s[6], s[7]);
    return pk;
}
__device__ __forceinline__ void calc_corners(float py, float px, int chbase,
    float& w00, float& w01, float& w10, float& w11,
    int& o00, int& o01, int& o10, int& o11)
{
    float y0f = floorf(py), x0f = floorf(px);
    float wy = py - y0f, wx = px - x0f;
    int iy0 = (int)y0f, ix0 = (int)x0f;
    float fy0 = (iy0 >= 0 && iy0 < 64) ? 1.f : 0.f;
    float fy1 = (iy0 >= -1 && iy0 < 63) ? 1.f : 0.f;
    float fx0 = (ix0 >= 0 && ix0 < 64) ? 1.f : 0.f;
    float fx1 = (ix0 >= -1 && ix0 < 63) ? 1.f : 0.f;
    int cy0 = min(max(iy0, 0), 63), cy1 = min(max(iy0 + 1, 0), 63);
    int cx0 = min(max(ix0, 0), 63), cx1 = min(max(ix0 + 1, 0), 63);
    w00 = (1.f - wy) * (1.f - wx) * fy0 * fx0;
    w01 = (1.f - wy) * wx * fy0 * fx1;
    w10 = wy * (1.f - wx) * fy1 * fx0;
    w11 = wy * wx * fy1 * fx1;
    o00 = (cy0 * 64 + cx0) * 128 + chbase;
    o01 = (cy0 * 64 + cx1) * 128 + chbase;
    o10 = (cy1 * 64 + cx0) * 128 + chbase;
    o11 = (cy1 * 64 + cx1) * 128 + chbase;
}

// ---------------- xt: NCHW fp32 -> NHWC bf16  (+ all weight packing) ----------------
__global__ __launch_bounds__(256) void xt_prep_kernel(
    const float* __restrict__ x, ushort_t* __restrict__ xt,
    const float* __restrict__ deform_w,   // (128,128,3,3)
    const float* __restrict__ offset_w,   // (18,128,3,3)
    const float* __restrict__ gamma,
    const float* __restrict__ beta,
    const float* __restrict__ rmean,
    const float* __restrict__ rvar,
    ushort_t* __restrict__ wA,    // [p][cout][c] bf16
    ushort_t* __restrict__ wOb,   // [32 (18 used)][k=tap*128+c] bf16
    float* __restrict__ scale,
    float* __restrict__ shift)
{
    __shared__ __align__(16) ushort_t tile[64 * 132];
    int braw = blockIdx.x;
    int b = ((braw & 7) << 7) + (braw >> 3);   // XCD k -> n {2k,2k+1}
    int n = b >> 6, h = b & 63;
    int t = threadIdx.x;

    int i = braw * 256 + t;
    if (i < 147456) {
        int p = i >> 14, o = (i >> 7) & 127, c = i & 127;
        wA[i] = f2b(deform_w[o * 1152 + c * 9 + p]);
    }
    if (i < 36864) {
        int row = i / 1152;
        int k = i - row * 1152;
        int tap = k >> 7, c = k & 127;
        wOb[i] = (row < 18) ? f2b(offset_w[row * 1152 + c * 9 + tap]) : (ushort_t)0;
    }
    if (i < 128) {
        float sc = gamma[i] * rsqrtf(rvar[i] + 1e-5f);
        scale[i] = sc;
        shift[i] = beta[i] - rmean[i] * sc;
    }

    int w = t & 63, c4 = t >> 6;
    for (int cb = 0; cb < 32; ++cb) {
        int c = cb * 4 + c4;
        tile[w * 132 + c] = f2b(x[((n * 128 + c) * 64 + h) * 64 + w]);
    }
    __syncthreads();
    for (int it = 0; it < 4; ++it) {
        int idx = it * 2048 + t * 8;
        int ww = idx >> 7, cc = idx & 127;
        short4v lo = *(const short4v*)(&tile[ww * 132 + cc]);
        short4v hi = *(const short4v*)(&tile[ww * 132 + cc + 4]);
        ushort_t* dst = xt + ((n * 64 + h) * 64 + ww) * 128 + cc;
        *(short4v*)(dst) = lo;
        *(short4v*)(dst + 4) = hi;
    }
}

// ---------------- fused: offset-conv (MFMA) + bilinear sample + GEMM + BN + SiLU ----------------
// one block per (n, ho) output row; 3 blocks/CU
__global__ __launch_bounds__(256, 3) void fused_kernel(
    const ushort_t* __restrict__ xt,      // (16,64,64,128) bf16
    const ushort_t* __restrict__ wA,      // [p][cout][c] bf16
    const ushort_t* __restrict__ wOb,     // [32][1152] bf16
    const float* __restrict__ offset_b,   // (18,)
    const float* __restrict__ scale,
    const float* __restrict__ shift,
    float* __restrict__ out)              // (16,128,64,64) fp32
{
    __shared__ __align__(16) char smem[50688];
    float*    posb = (float*)smem;                 // [18][64] fp32 (phase 3)
    ushort_t* sxp  = (ushort_t*)smem;              // [3][66][128] bf16 (phases 1-2)
    ushort_t* S0   = (ushort_t*)(smem + 8192);     // 2 x [64][128] bf16 (phase 3)

    int braw = blockIdx.x;
    int b = ((braw & 7) << 7) + (braw >> 3);       // XCD slab swizzle
    int n = b >> 6, ho = b & 63;
    int t = threadIdx.x;
    int lane = t & 63;
    int wv = __builtin_amdgcn_readfirstlane(t >> 6);

    const ushort_t* xn = xt + n * (64 * 64 * 128);

    // ---- phase 1: stage rows ho-1..ho+1, col-padded (66), granule-swizzled ----
    for (int i = t; i < 3168; i += 256) {
        int r = (i >= 2112) ? 2 : ((i >= 1056) ? 1 : 0);
        int rem = i - r * 1056;
        int colp = rem >> 4, g = rem & 15;
        int row = ho - 1 + r, col = colp - 1;
        short8v v = {0, 0, 0, 0, 0, 0, 0, 0};
        if (row >= 0 && row < 64 && col >= 0 && col < 64)
            v = *(const short8v*)(xn + (row * 64 + col) * 128 + g * 8);
        int gg = g ^ (colp & 15);
        *(short8v*)(sxp + (r * 66 + colp) * 128 + gg * 8) = v;
    }
    __syncthreads();

    // ---- phase 2: offset conv via mfma 16x16x32 (M=32pad, N=16/wave, K=1152) ----
    {
        f32x4 acc2[2];
        #pragma unroll
        for (int mt = 0; mt < 2; ++mt)
            #pragma unroll
            for (int r = 0; r < 4; ++r) acc2[mt][r] = 0.f;

        int m = lane & 15, kq = lane >> 4;
        int pixq = wv * 16 + m;
        #pragma unroll
        for (int ks = 0; ks < 36; ++ks) {
            const int tap = ks >> 2, cq = ks & 3;
            const int krow = tap / 3, kx = tap % 3;     // constants after unroll
            bf16x8 a0 = *(const bf16x8*)(wOb + m * 1152 + tap * 128 + cq * 32 + kq * 8);
            bf16x8 a1 = *(const bf16x8*)(wOb + (16 + m) * 1152 + tap * 128 + cq * 32 + kq * 8);
            int colp = pixq + kx;
            int gg = (cq * 4 + kq) ^ (colp & 15);
            bf16x8 bf = *(const bf16x8*)(sxp + (krow * 66 + colp) * 128 + gg * 8);
            acc2[0] = __builtin_amdgcn_mfma_f32_16x16x32_bf16(a0, bf, acc2[0], 0, 0, 0);
            acc2[1] = __builtin_amdgcn_mfma_f32_16x16x32_bf16(a1, bf, acc2[1], 0, 0, 0);
        }
        __syncthreads();     // all sxp reads done before pos overwrites smem base
        #pragma unroll
        for (int mt = 0; mt < 2; ++mt)
            #pragma unroll
            for (int r = 0; r < 4; ++r) {
                int oc = mt * 16 + kq * 4 + r;
                if (oc < 18) {
                    float v = acc2[mt][r] + offset_b[oc];
                    int pp = oc >> 1;
                    v += (oc & 1) ? (float)(pp % 3 - 1 + pixq) : (float)(pp / 3 - 1 + ho);
                    posb[oc * 64 + pixq] = v;
                }
            }
    }
    __syncthreads();

    // ---- phase 3: deform sampling + MFMA GEMM, double-buffered, 1 barrier/p ----
    int pix_s = lane;                 // sampling pixel = lane; channel group = wave
    int chbase = wv * 32;
    int mh = wv >> 1, nh = wv & 1;

    f32x16 acc[2];
    #pragma unroll
    for (int mt = 0; mt < 2; ++mt)
        #pragma unroll
        for (int r = 0; r < 16; ++r) acc[mt][r] = 0.f;

    float w00, w01, w10, w11;
    int o00, o01, o10, o11;
    short8v v00[2], v01[2], v10[2], v11[2];

    // prologue p=0
    calc_corners(posb[pix_s], posb[64 + pix_s], chbase, w00, w01, w10, w11, o00, o01, o10, o11);
    #pragma unroll
    for (int g = 0; g < 2; ++g) {
        v00[g] = *(const short8v*)(xn + o00 + g * 8);
        v01[g] = *(const short8v*)(xn + o01 + g * 8);
        v10[g] = *(const short8v*)(xn + o10 + g * 8);
        v11[g] = *(const short8v*)(xn + o11 + g * 8);
    }

    for (int p = 0; p < 9; ++p) {
        ushort_t* buf = S0 + (p & 1) * 8192;

        // second-half corner loads (granules 2,3) in flight during blends
        short8v u00[2], u01[2], u10[2], u11[2];
        #pragma unroll
        for (int g = 0; g < 2; ++g) {
            u00[g] = *(const short8v*)(xn + o00 + (g + 2) * 8);
            u01[g] = *(const short8v*)(xn + o01 + (g + 2) * 8);
            u10[g] = *(const short8v*)(xn + o10 + (g + 2) * 8);
            u11[g] = *(const short8v*)(xn + o11 + (g + 2) * 8);
        }
        #pragma unroll
        for (int g = 0; g < 2; ++g) {
            uint4 pk = blend_pack(v00[g], v01[g], v10[g], v11[g], w00, w01, w10, w11);
            int gg = (wv * 4 + g) ^ (pix_s & 15);
            *(uint4*)(buf + pix_s * 128 + gg * 8) = pk;
        }
        #pragma unroll
        for (int g = 0; g < 2; ++g) {
            uint4 pk = blend_pack(u00[g], u01[g], u10[g], u11[g], w00, w01, w10, w11);
            int gg = (wv * 4 + g + 2) ^ (pix_s & 15);
            *(uint4*)(buf + pix_s * 128 + gg * 8) = pk;
        }

        if (p < 8) {   // prefetch next p: positions (LDS, stable) + first-half corners
            calc_corners(posb[(2 * p + 2) * 64 + pix_s], posb[(2 * p + 3) * 64 + pix_s],
                         chbase, w00, w01, w10, w11, o00, o01, o10, o11);
            #pragma unroll
            for (int g = 0; g < 2; ++g) {
                v00[g] = *(const short8v*)(xn + o00 + g * 8);
                v01[g] = *(const short8v*)(xn + o01 + g * 8);
                v10[g] = *(const short8v*)(xn + o10 + g * 8);
                v11[g] = *(const short8v*)(xn + o11 + g * 8);
            }
        }

        __syncthreads();   // stores visible; prior-p MFMA readers done (alt buffer)

        const ushort_t* wAp = wA + p * 16384;
        int coutA = mh * 64 + (lane & 31);
        int pixb = nh * 32 + (lane & 31);
        #pragma unroll
        for (int ks = 0; ks < 8; ++ks) {
            bf16x8 a0 = *(const bf16x8*)(wAp + coutA * 128 + ks * 16 + ((lane >> 5) << 3));
            bf16x8 a1 = *(const bf16x8*)(wAp + (coutA + 32) * 128 + ks * 16 + ((lane >> 5) << 3));
            int gg = (ks * 2 + (lane >> 5)) ^ (pixb & 15);
            bf16x8 bfrag = *(const bf16x8*)(buf + pixb * 128 + gg * 8);
            acc[0] = __builtin_amdgcn_mfma_f32_32x32x16_bf16(a0, bfrag, acc[0], 0, 0, 0);
            acc[1] = __builtin_amdgcn_mfma_f32_32x32x16_bf16(a1, bfrag, acc[1], 0, 0, 0);
        }
    }

    // ---- epilogue: BN + SiLU ----
    int pixb = nh * 32 + (lane & 31);
    #pragma unroll
    for (int mt = 0; mt < 2; ++mt) {
        #pragma unroll
        for (int r = 0; r < 16; ++r) {
            int cout = mh * 64 + mt * 32 + (r & 3) + 8 * (r >> 2) + 4 * (lane >> 5);
            float v = acc[mt][r] * scale[cout] + shift[cout];
            float rr = v / (1.f + __expf(-v));
            out[((n * 128 + cout) * 64 + ho) * 64 + pixb] = rr;
        }
    }
}

extern "C" void kernel_launch(void* const* d_in, const int* in_sizes, int n_in,
                              void* d_out, int out_size, void* d_ws, size_t ws_size,
                              hipStream_t stream) {
    const float* x        = (const float*)d_in[0];
    const float* offset_w = (const float*)d_in[1];
    const float* offset_b = (const float*)d_in[2];
    const float* deform_w = (const float*)d_in[3];
    const float* gamma    = (const float*)d_in[4];
    const float* beta     = (const float*)d_in[5];
    const float* rmean    = (const float*)d_in[6];
    const float* rvar     = (const float*)d_in[7];

    char* ws = (char*)d_ws;
    ushort_t* xt    = (ushort_t*)(ws);               // 16,777,216 B
    ushort_t* wA    = (ushort_t*)(ws + 16777216);    //    294,912 B
    ushort_t* wOb   = (ushort_t*)(ws + 17072128);    //     73,728 B
    float*    scale = (float*)(ws + 17145856);       //        512 B
    float*    shift = (float*)(ws + 17146368);       //        512 B
    float*    out   = (float*)d_out;

    hipLaunchKernelGGL(xt_prep_kernel, dim3(1024), dim3(256), 0, stream,
                       x, xt, deform_w, offset_w, gamma, beta, rmean, rvar,
                       wA, wOb, scale, shift);
    hipLaunchKernelGGL(fused_kernel, dim3(1024), dim3(256), 0, stream,
                       xt, wA, wOb, offset_b, scale, shift, out);
}